// Round 6
// baseline (556.946 us; speedup 1.0000x reference)
//
#include <hip/hip_runtime.h>
#include <hip/hip_bf16.h>

#define THREADS 256
#define HP 136     // padded LDS row stride (shorts) for h rows
#define FEXP 20    // fex row stride in f32 (16 + 4 pad)

typedef float f32x4 __attribute__((ext_vector_type(4)));
typedef short s16x8 __attribute__((ext_vector_type(8)));

static __device__ __forceinline__ short f2b(float x) {
    return __builtin_bit_cast(short, __float2bfloat16(x));
}
static __device__ __forceinline__ float b2f(short u) {
    unsigned int v = ((unsigned int)(unsigned short)u) << 16;
    return __builtin_bit_cast(float, v);
}
static __device__ __forceinline__ void split8(const f32x4 a, const f32x4 b, s16x8& hi, s16x8& lo) {
    #pragma unroll
    for (int j = 0; j < 4; ++j) {
        short h0 = f2b(a[j]); hi[j]   = h0; lo[j]   = f2b(a[j] - b2f(h0));
        short h1 = f2b(b[j]); hi[j+4] = h1; lo[j+4] = f2b(b[j] - b2f(h1));
    }
}
static __device__ __forceinline__ s16x8 cvt8(const f32x4 a, const f32x4 b) {
    s16x8 r;
    r[0]=f2b(a[0]); r[1]=f2b(a[1]); r[2]=f2b(a[2]); r[3]=f2b(a[3]);
    r[4]=f2b(b[0]); r[5]=f2b(b[1]); r[6]=f2b(b[2]); r[7]=f2b(b[3]);
    return r;
}
static __device__ __forceinline__ float sigm(float x) { return 1.0f / (1.0f + __expf(-x)); }

static __device__ __forceinline__ void gload16(const short* g, short* l3) {
    __builtin_amdgcn_global_load_lds((const __attribute__((address_space(1))) void*)g,
                                     (__attribute__((address_space(3))) void*)l3, 16, 0, 0);
}

#define MFMA16(A,B,C) __builtin_amdgcn_mfma_f32_16x16x32_bf16((A),(B),(C),0,0,0)

// Counted-vmcnt barrier (two-level so macro args expand before stringize).
#define WAITBAR_(N) do {                                            \
    asm volatile("s_waitcnt vmcnt(" #N ")" ::: "memory");           \
    __builtin_amdgcn_s_barrier();                                   \
    asm volatile("" ::: "memory"); } while (0)
#define WAITBAR(N) WAITBAR_(N)
// Buffer-release barrier: this wave's ds_reads retired, then block sync.
#define RELBAR() do {                                               \
    asm volatile("s_waitcnt lgkmcnt(0)" ::: "memory");              \
    __builtin_amdgcn_s_barrier();                                   \
    asm volatile("" ::: "memory"); } while (0)

// ---- pre-pass: build swizzled hi/lo weight image + W2 bf16 -------------------
// image (shorts): chunk cp (32 KB): [fz][plane][n][slot*8], slot = kg ^ ((n>>1)&3)
// 32 chunks * 16384 shorts = 524288 (1 MB); then W2 bf16 [128][128] = 16384.
__global__ __launch_bounds__(256) void itemfusing_prep(
    const float* __restrict__ Wf1, const float* __restrict__ Wf2,
    const float* __restrict__ W2, short* __restrict__ wsp)
{
    const int t = blockIdx.x * 256 + threadIdx.x;
    if (t < 65536) {
        const int kg = t & 3;
        const int n  = (t >> 2) & 127;
        const int pl = (t >> 9) & 1;
        const int cp = (t >> 10) & 31;
        const int fz = (t >> 15) & 1;
        const float* src = (fz ? Wf2 : Wf1) + (size_t)n * 1024 + cp * 32 + kg * 8;
        s16x8 hi, lo; split8(*(const f32x4*)src, *(const f32x4*)(src + 4), hi, lo);
        const int slot = kg ^ ((n >> 1) & 3);
        *(s16x8*)(wsp + (size_t)cp * 16384 + fz * 8192 + pl * 4096 + n * 32 + slot * 8)
            = pl ? lo : hi;
    } else if (t < 65536 + 2048) {
        const int i = (t - 65536) * 8;
        const float* src = W2 + i;
        *(s16x8*)(wsp + 524288 + i) = cvt8(*(const f32x4*)src, *(const f32x4*)(src + 4));
    }
}

// ---- main: 4 waves = (session pr, weight fz); M=32/wave; 32 K-chunks ---------
__global__ __launch_bounds__(THREADS, 2) void itemfusing_main(
    const float* __restrict__ inter, const float* __restrict__ intra,
    const float* __restrict__ bf1, const float* __restrict__ bf2,
    const float* __restrict__ W1,  const float* __restrict__ b1,
    const float* __restrict__ b2,
    const float* __restrict__ qw,  const float* __restrict__ qb,
    const float* __restrict__ W3,  const float* __restrict__ b3,
    const short* __restrict__ gimg, const short* __restrict__ w2b,
    float* __restrict__ out)
{
    __shared__ union {
        short wimg[2][2][2][128][32];        // [p][fz][pl][n][slot] = 65536 B
        struct {
            float fex [2][2][128][FEXP];     // 40960 B
            short hbuf[2][32][HP];           // 17408 B
            float vnb [2][128];              // 1024 B
            float w1vb[2][128];              // 1024 B
            float sglp[2][2][128];           // 2048 B
        } t;
    } u;                                     // static 65536 B -> 2 blocks/CU

    const int tid = threadIdx.x;
    const int l   = tid & 63;
    const int l15 = l & 15;
    const int kg  = l >> 4;
    const int w   = tid >> 6;
    const int pr  = w >> 1;      // session slot 0..1
    const int fz  = w & 1;       // 0: f1 (inter,Wf1)  1: f2 (intra,Wf2)
    const int sess = blockIdx.x * 2 + pr;
    const int slot8 = (kg ^ ((l15 >> 1) & 3)) * 8;

    const float* Aemb = (fz ? intra : inter) + ((size_t)(sess * 32 + l15) * 1024 + kg * 8);
    short* lbase = &u.wimg[0][0][0][0][0];

    f32x4 acc0[8], acc1[8];
    #pragma unroll
    for (int nt = 0; nt < 8; ++nt) {
        acc0[nt] = f32x4{0.f, 0.f, 0.f, 0.f};
        acc1[nt] = f32x4{0.f, 0.f, 0.f, 0.f};
    }

    // named A register double-buffer (rule #20: no runtime-indexed arrays)
    f32x4 AE0, AE1, AE2, AE3, AO0, AO1, AO2, AO3;

#define ISSUE_B(CP, P) do {                                                     \
    _Pragma("unroll")                                                           \
    for (int j_ = 0; j_ < 8; ++j_)                                              \
        gload16(gimg + (size_t)(CP) * 16384 + (w * 8 + j_) * 512 + l * 8,       \
                lbase + (P) * 16384 + (w * 8 + j_) * 512);                      \
    } while (0)

#define ISSUE_A(S, CP) do {                                                     \
    const float* p_ = Aemb + (CP) * 32;                                         \
    S##0 = *(const f32x4*)p_;  S##1 = *(const f32x4*)(p_ + 4);                  \
    const float* q_ = p_ + (size_t)16 * 1024;                                   \
    S##2 = *(const f32x4*)q_;  S##3 = *(const f32x4*)(q_ + 4); } while (0)

#define COMPUTE(P, S) do {                                                      \
    s16x8 ah0, al0, ah1, al1;                                                   \
    split8(S##0, S##1, ah0, al0);                                               \
    split8(S##2, S##3, ah1, al1);                                               \
    const short* fb_ = lbase + (P) * 16384 + fz * 8192 + l15 * 32 + slot8;      \
    _Pragma("unroll")                                                           \
    for (int nt_ = 0; nt_ < 8; ++nt_) {                                         \
        s16x8 bh_ = *(const s16x8*)(fb_ + nt_ * 512);                           \
        s16x8 bl_ = *(const s16x8*)(fb_ + 4096 + nt_ * 512);                    \
        acc0[nt_] = MFMA16(ah0, bh_, acc0[nt_]);                                \
        acc1[nt_] = MFMA16(ah1, bh_, acc1[nt_]);                                \
        acc0[nt_] = MFMA16(al0, bh_, acc0[nt_]);                                \
        acc1[nt_] = MFMA16(al1, bh_, acc1[nt_]);                                \
        acc0[nt_] = MFMA16(ah0, bl_, acc0[nt_]);                                \
        acc1[nt_] = MFMA16(ah1, bl_, acc1[nt_]);                                \
    } } while (0)

#define BODY(C2, S, P, DOISSUE, VN) do {                                        \
    WAITBAR(VN);                                                                \
    COMPUTE(P, S);                                                              \
    RELBAR();                                                                   \
    if (DOISSUE) { ISSUE_B((C2) + 2, P); ISSUE_A(S, (C2) + 2); } } while (0)

    // prologue: chunks 0 and 1 fully in flight (12 vm-ops each per wave)
    ISSUE_B(0, 0); ISSUE_A(AE, 0);
    ISSUE_B(1, 1); ISSUE_A(AO, 1);

    #pragma unroll 1
    for (int c = 0; c < 30; c += 2) {
        BODY(c,     AE, 0, true, 12);
        BODY(c + 1, AO, 1, true, 12);
    }
    BODY(30, AE, 0, false, 12);
    BODY(31, AO, 1, false, 0);     // final RELBAR: LDS free for tail union

#undef ISSUE_B
#undef ISSUE_A
#undef COMPUTE
#undef BODY

    // ---------------- exchange: give paired wave its missing weight half ---------
    if (fz == 0) {
        #pragma unroll
        for (int nt = 0; nt < 8; ++nt)
            *(f32x4*)&u.t.fex[pr][0][nt * 16 + l15][kg * 4] = acc1[nt];  // f1 rows 16-31
    } else {
        #pragma unroll
        for (int nt = 0; nt < 8; ++nt)
            *(f32x4*)&u.t.fex[pr][1][nt * 16 + l15][kg * 4] = acc0[nt];  // f2 rows 0-15
    }
    __syncthreads();   // B1

    // ---------------- gate: h for own 16 rows (row = fz*16 + kg*4 + rj) ----------
    f32x4 hreg[8];
    #pragma unroll
    for (int nt = 0; nt < 8; ++nt) {
        const int n = nt * 16 + l15;
        f32x4 oth = *(const f32x4*)&u.t.fex[pr][1 - fz][n][kg * 4];
        f32x4 own = fz ? acc1[nt] : acc0[nt];
        const float bb1 = bf1[n], bb2 = bf2[n];
        #pragma unroll
        for (int rj = 0; rj < 4; ++rj) {
            float x1 = (fz ? oth[rj] : own[rj]) + bb1;
            float x2 = (fz ? own[rj] : oth[rj]) + bb2;
            float g  = sigm(x1 + x2);
            hreg[nt][rj] = x2 + g * (x1 - x2);
        }
    }

    // v_n (session row 31 = fz1 wave, kg=3, rj=3) + h rows -> LDS
    if (fz == 1 && kg == 3) {
        #pragma unroll
        for (int nt = 0; nt < 8; ++nt) u.t.vnb[pr][nt * 16 + l15] = hreg[nt][3];
    }
    #pragma unroll
    for (int nt = 0; nt < 8; ++nt)
        #pragma unroll
        for (int rj = 0; rj < 4; ++rj)
            u.t.hbuf[pr][fz * 16 + kg * 4 + rj][nt * 16 + l15] = f2b(hreg[nt][rj]);
    __syncthreads();   // B2: vn + hbuf visible

    // ---------------- w1v = W1 @ v_n + b1 (64 outputs per wave) ------------------
    {
        const int n = fz * 64 + l;
        const float* w1r = W1 + (size_t)n * 128;
        float a = b1[n];
        #pragma unroll
        for (int kk = 0; kk < 128; kk += 4) {
            f32x4 vv = *(const f32x4*)&u.t.vnb[pr][kk];
            f32x4 u0 = *(const f32x4*)(w1r + kk);
            #pragma unroll
            for (int j = 0; j < 4; ++j) a += u0[j] * vv[j];
        }
        u.t.w1vb[pr][n] = a;
    }

    // ---------------- w2h = h @ W2^T (MFMA, own 16 rows) -------------------------
    f32x4 aw[8];
    #pragma unroll
    for (int nt = 0; nt < 8; ++nt) aw[nt] = f32x4{0.f, 0.f, 0.f, 0.f};
    #pragma unroll
    for (int ks = 0; ks < 4; ++ks) {
        const int kl = ks * 32 + kg * 8;
        s16x8 ah = *(const s16x8*)&u.t.hbuf[pr][fz * 16 + l15][kl];
        #pragma unroll
        for (int nt = 0; nt < 8; ++nt) {
            s16x8 bw = *(const s16x8*)&w2b[(size_t)(nt * 16 + l15) * 128 + kl];
            aw[nt] = MFMA16(ah, bw, aw[nt]);
        }
    }
    __syncthreads();   // B3: w1vb visible

    // ---------------- alpha rows (own 16 rows, wave-local) -----------------------
    float prt[4] = {0.f, 0.f, 0.f, 0.f};
    #pragma unroll
    for (int nt = 0; nt < 8; ++nt) {
        const int n = nt * 16 + l15;
        const float qn = qw[n], wv_ = u.t.w1vb[pr][n], bb = b2[n];
        #pragma unroll
        for (int rj = 0; rj < 4; ++rj)
            prt[rj] += qn * sigm(wv_ + aw[nt][rj] + bb);
    }
    const float qbias = qb[0];
    #pragma unroll
    for (int rj = 0; rj < 4; ++rj) {
        float v = prt[rj];
        v += __shfl_xor(v, 1); v += __shfl_xor(v, 2);
        v += __shfl_xor(v, 4); v += __shfl_xor(v, 8);
        prt[rj] = v + qbias;          // alpha for row fz*16 + kg*4 + rj
    }

    // ---------------- s_g partial over own 16 rows -------------------------------
    #pragma unroll
    for (int nt = 0; nt < 8; ++nt) {
        float sgv = 0.f;
        #pragma unroll
        for (int rj = 0; rj < 4; ++rj) sgv += prt[rj] * hreg[nt][rj];
        sgv += __shfl_xor(sgv, 16);
        sgv += __shfl_xor(sgv, 32);
        if (l < 16) u.t.sglp[pr][fz][nt * 16 + l15] = sgv;
    }
    __syncthreads();   // B4

    // ---------------- out = W3 @ [v_n ; s_g] + b3 --------------------------------
    {
        const int n = fz * 64 + l;
        const float* w3r = W3 + (size_t)n * 256;
        float o = b3[n];
        #pragma unroll
        for (int kk = 0; kk < 128; kk += 4) {
            f32x4 vv = *(const f32x4*)&u.t.vnb[pr][kk];
            f32x4 s0 = *(const f32x4*)&u.t.sglp[pr][0][kk];
            f32x4 s1 = *(const f32x4*)&u.t.sglp[pr][1][kk];
            f32x4 a0 = *(const f32x4*)(w3r + kk);
            f32x4 c0 = *(const f32x4*)(w3r + 128 + kk);
            #pragma unroll
            for (int j = 0; j < 4; ++j)
                o += a0[j] * vv[j] + c0[j] * (s0[j] + s1[j]);
        }
        out[(size_t)sess * 128 + n] = o;
    }
}

// ---- naive fallback (only if ws too small; correctness insurance) ------------
__global__ __launch_bounds__(128) void itemfusing_naive(
    const float* __restrict__ inter, const float* __restrict__ intra,
    const float* __restrict__ Wf1, const float* __restrict__ bf1,
    const float* __restrict__ Wf2, const float* __restrict__ bf2,
    const float* __restrict__ W1,  const float* __restrict__ b1,
    const float* __restrict__ W2,  const float* __restrict__ b2,
    const float* __restrict__ qw,  const float* __restrict__ qb,
    const float* __restrict__ W3,  const float* __restrict__ b3,
    float* __restrict__ out)
{
    __shared__ float h[32][128];
    __shared__ float vn[128], w1v[128], al[32], sg[128], red[128];
    const int n = threadIdx.x; const int sess = blockIdx.x;
    for (int t0 = 0; t0 < 32; ++t0) {
        const float* e1 = inter + (size_t)(sess * 32 + t0) * 1024;
        const float* e2 = intra + (size_t)(sess * 32 + t0) * 1024;
        const float* r1 = Wf1 + (size_t)n * 1024;
        const float* r2 = Wf2 + (size_t)n * 1024;
        float s1 = bf1[n], s2 = bf2[n];
        for (int k = 0; k < 1024; ++k) { s1 += e1[k] * r1[k]; s2 += e2[k] * r2[k]; }
        float g = sigm(s1 + s2);
        h[t0][n] = s2 + g * (s1 - s2);
    }
    __syncthreads();
    vn[n] = h[31][n];
    __syncthreads();
    { float a = b1[n]; const float* w1r = W1 + (size_t)n * 128;
      for (int k = 0; k < 128; ++k) a += w1r[k] * vn[k];
      w1v[n] = a; }
    __syncthreads();
    for (int t0 = 0; t0 < 32; ++t0) {
        float x = b2[n]; const float* w2r = W2 + (size_t)n * 128;
        for (int k = 0; k < 128; ++k) x += w2r[k] * h[t0][k];
        red[n] = qw[n] * sigm(w1v[n] + x); __syncthreads();
        for (int s_ = 64; s_ > 0; s_ >>= 1) { if (n < s_) red[n] += red[n + s_]; __syncthreads(); }
        if (n == 0) al[t0] = red[0] + qb[0];
        __syncthreads();
    }
    { float s = 0.f; for (int t0 = 0; t0 < 32; ++t0) s += al[t0] * h[t0][n];
      sg[n] = s; }
    __syncthreads();
    { float o = b3[n]; const float* w3r = W3 + (size_t)n * 256;
      for (int k = 0; k < 128; ++k) o += w3r[k] * vn[k] + w3r[128 + k] * sg[k];
      out[(size_t)sess * 128 + n] = o; }
}

extern "C" void kernel_launch(void* const* d_in, const int* in_sizes, int n_in,
                              void* d_out, int out_size, void* d_ws, size_t ws_size,
                              hipStream_t stream) {
    (void)n_in; (void)out_size;
    const float* inter = (const float*)d_in[0];
    const float* intra = (const float*)d_in[1];
    const float* Wf1   = (const float*)d_in[3];
    const float* bf1   = (const float*)d_in[4];
    const float* Wf2   = (const float*)d_in[5];
    const float* bf2   = (const float*)d_in[6];
    const float* W1    = (const float*)d_in[7];
    const float* b1    = (const float*)d_in[8];
    const float* W2    = (const float*)d_in[9];
    const float* b2    = (const float*)d_in[10];
    const float* qw    = (const float*)d_in[11];
    const float* qb    = (const float*)d_in[12];
    const float* W3    = (const float*)d_in[13];
    const float* b3    = (const float*)d_in[14];
    float* out = (float*)d_out;

    const int nsess = in_sizes[2];               // 4096
    const size_t WS_NEED = (size_t)(524288 + 16384) * sizeof(short);

    if (d_ws != nullptr && ws_size >= WS_NEED) {
        short* wsp = (short*)d_ws;
        itemfusing_prep<<<264, 256, 0, stream>>>(Wf1, Wf2, W2, wsp);
        itemfusing_main<<<nsess / 2, THREADS, 0, stream>>>(
            inter, intra, bf1, bf2, W1, b1, b2, qw, qb, W3, b3,
            wsp, wsp + 524288, out);
    } else {
        itemfusing_naive<<<nsess, 128, 0, stream>>>(
            inter, intra, Wf1, bf1, Wf2, bf2, W1, b1, W2, b2, qw, qb, W3, b3, out);
    }
}

// Round 7
// 383.199 us; speedup vs baseline: 1.4534x; 1.4534x over previous
//
#include <hip/hip_runtime.h>
#include <hip/hip_bf16.h>

#define THREADS 512
#define HP 136     // padded LDS row stride (shorts) for h rows

typedef float f32x4 __attribute__((ext_vector_type(4)));
typedef short s16x8 __attribute__((ext_vector_type(8)));

static __device__ __forceinline__ short f2b(float x) {
    return __builtin_bit_cast(short, __float2bfloat16(x));
}
static __device__ __forceinline__ float b2f(short u) {
    unsigned int v = ((unsigned int)(unsigned short)u) << 16;
    return __builtin_bit_cast(float, v);
}
static __device__ __forceinline__ void split8(const f32x4 a, const f32x4 b, s16x8& hi, s16x8& lo) {
    #pragma unroll
    for (int j = 0; j < 4; ++j) {
        short h0 = f2b(a[j]); hi[j]   = h0; lo[j]   = f2b(a[j] - b2f(h0));
        short h1 = f2b(b[j]); hi[j+4] = h1; lo[j+4] = f2b(b[j] - b2f(h1));
    }
}
static __device__ __forceinline__ s16x8 cvt8(const f32x4 a, const f32x4 b) {
    s16x8 r;
    r[0]=f2b(a[0]); r[1]=f2b(a[1]); r[2]=f2b(a[2]); r[3]=f2b(a[3]);
    r[4]=f2b(b[0]); r[5]=f2b(b[1]); r[6]=f2b(b[2]); r[7]=f2b(b[3]);
    return r;
}
static __device__ __forceinline__ float sigm(float x) { return 1.0f / (1.0f + __expf(-x)); }

#define MFMA16(A,B,C) __builtin_amdgcn_mfma_f32_16x16x32_bf16((A),(B),(C),0,0,0)

// ---- pre-pass: build XOR-swizzled hi/lo weight image + W2 bf16 ---------------
// image (shorts): chunk cp (32 KB): [fz][plane][n][slot*8], slot = kg ^ ((n>>1)&3)
// 32 chunks * 16384 shorts = 524288 (1 MB); then W2 bf16 [128][128] = 16384.
__global__ __launch_bounds__(256) void itemfusing_prep(
    const float* __restrict__ Wf1, const float* __restrict__ Wf2,
    const float* __restrict__ W2, short* __restrict__ wsp)
{
    const int t = blockIdx.x * 256 + threadIdx.x;
    if (t < 65536) {
        const int kg = t & 3;
        const int n  = (t >> 2) & 127;
        const int pl = (t >> 9) & 1;
        const int cp = (t >> 10) & 31;
        const int fz = (t >> 15) & 1;
        const float* src = (fz ? Wf2 : Wf1) + (size_t)n * 1024 + cp * 32 + kg * 8;
        s16x8 hi, lo; split8(*(const f32x4*)src, *(const f32x4*)(src + 4), hi, lo);
        const int slot = kg ^ ((n >> 1) & 3);
        *(s16x8*)(wsp + (size_t)cp * 16384 + fz * 8192 + pl * 4096 + n * 32 + slot * 8)
            = pl ? lo : hi;
    } else if (t < 65536 + 2048) {
        const int i = (t - 65536) * 8;
        const float* src = W2 + i;
        *(s16x8*)(wsp + 524288 + i) = cvt8(*(const f32x4*)src, *(const f32x4*)(src + 4));
    }
}

// ---- main: R2 structure (512 thr, 8 waves = 8 sessions, M=32/wave) -----------
// Phase 1 stages pre-split image chunks by pure s16x8 copy (no VALU split),
// reads B-frags with the validated XOR slot (low bank conflict).
__global__ __launch_bounds__(THREADS, 2) void itemfusing_main(
    const float* __restrict__ inter, const float* __restrict__ intra,
    const float* __restrict__ bf1, const float* __restrict__ bf2,
    const float* __restrict__ W1,  const float* __restrict__ b1,
    const float* __restrict__ b2,
    const float* __restrict__ qw,  const float* __restrict__ qb,
    const float* __restrict__ W3,  const float* __restrict__ b3,
    const short* __restrict__ gimg, const short* __restrict__ w2b,
    float* __restrict__ out)
{
    __shared__ union {
        short wbuf[2][2][128][32];   // [weight-buf][plane][n][k-slot] : 32768 B
        short hbuf[4][32][HP];       // h rows for 4 waves            : 34816 B
    } u;
    __shared__ float vn [8][128];    // 4096 B
    __shared__ float w1v[8][128];    // 4096 B
    __shared__ float sgl[8][128];    // 4096 B   -> static total 47104 B

    const int tid = threadIdx.x;
    const int w   = tid >> 6;        // wave id == session slot (0..7)
    const int l   = tid & 63;
    const int l15 = l & 15;
    const int kg  = l >> 4;
    const int sess = blockIdx.x * 8 + w;
    const int row0 = sess * 32;
    const int slot8 = (kg ^ ((l15 >> 1) & 3)) * 8;

    const float* A1 = inter + (size_t)(row0 + l15) * 1024 + kg * 8;
    const float* A2 = intra + (size_t)(row0 + l15) * 1024 + kg * 8;
    short* wb = &u.wbuf[0][0][0][0];

    f32x4 acc1[2][8], acc2[2][8];
    #pragma unroll
    for (int mt = 0; mt < 2; ++mt)
        #pragma unroll
        for (int nt = 0; nt < 8; ++nt) {
            acc1[mt][nt] = f32x4{0.f,0.f,0.f,0.f};
            acc2[mt][nt] = f32x4{0.f,0.f,0.f,0.f};
        }

    // staging: thread copies 16 shorts of one weight chunk (8192 shorts / 512 thr)
    s16x8 wrA, wrB;
#define WLOADR(FZ, CP) do {                                                     \
    const short* p_ = gimg + (size_t)(CP) * 16384 + (FZ) * 8192 + tid * 16;     \
    wrA = *(const s16x8*)p_; wrB = *(const s16x8*)(p_ + 8); } while (0)
#define WSTORE(BUF) do {                                                        \
    short* d_ = wb + (BUF) * 8192 + tid * 16;                                   \
    *(s16x8*)d_ = wrA; *(s16x8*)(d_ + 8) = wrB; } while (0)
#define ALOAD(R0, R1, R2_, R3_, AP, CP) do {                                    \
    const float* p_ = (AP) + (CP) * 32;                                         \
    R0 = *(const f32x4*)p_;  R1 = *(const f32x4*)(p_ + 4);                      \
    const float* q_ = p_ + (size_t)16 * 1024;                                   \
    R2_ = *(const f32x4*)q_; R3_ = *(const f32x4*)(q_ + 4); } while (0)
#define COMPUTE(BUF, ACC, R0, R1, R2_, R3_) do {                                \
    s16x8 ah0, al0, ah1, al1;                                                   \
    split8(R0, R1, ah0, al0);                                                   \
    split8(R2_, R3_, ah1, al1);                                                 \
    const short* fb_ = wb + (BUF) * 8192 + l15 * 32 + slot8;                    \
    _Pragma("unroll")                                                           \
    for (int nt_ = 0; nt_ < 8; ++nt_) {                                         \
        s16x8 bh_ = *(const s16x8*)(fb_ + nt_ * 512);                           \
        s16x8 bl_ = *(const s16x8*)(fb_ + 4096 + nt_ * 512);                    \
        ACC[0][nt_] = MFMA16(ah0, bh_, ACC[0][nt_]);                            \
        ACC[1][nt_] = MFMA16(ah1, bh_, ACC[1][nt_]);                            \
        ACC[0][nt_] = MFMA16(al0, bh_, ACC[0][nt_]);                            \
        ACC[1][nt_] = MFMA16(al1, bh_, ACC[1][nt_]);                            \
        ACC[0][nt_] = MFMA16(ah0, bl_, ACC[0][nt_]);                            \
        ACC[1][nt_] = MFMA16(ah1, bl_, ACC[1][nt_]);                            \
    } } while (0)

    f32x4 r10, r11, r12, r13;   // A(inter) regs
    f32x4 r20, r21, r22, r23;   // A(intra) regs

    // prologue: buf0 <- Wf1 c0; regs <- Wf2 c0; A regs <- c0
    WLOADR(0, 0); WSTORE(0);
    WLOADR(1, 0);
    ALOAD(r10, r11, r12, r13, A1, 0);
    ALOAD(r20, r21, r22, r23, A2, 0);
    __syncthreads();

    #pragma unroll 1
    for (int cp = 0; cp < 32; ++cp) {
        const bool more = (cp < 31);
        {   // EVEN: stage Wf2 cp -> buf1; prefetch Wf1 cp+1; compute acc1 from buf0
            WSTORE(1);
            if (more) WLOADR(0, cp + 1);
            COMPUTE(0, acc1, r10, r11, r12, r13);
            if (more) ALOAD(r10, r11, r12, r13, A1, cp + 1);
        }
        __syncthreads();
        {   // ODD: stage Wf1 cp+1 -> buf0; prefetch Wf2 cp+1; compute acc2 from buf1
            if (more) { WSTORE(0); WLOADR(1, cp + 1); }
            COMPUTE(1, acc2, r20, r21, r22, r23);
            if (more) ALOAD(r20, r21, r22, r23, A2, cp + 1);
        }
        __syncthreads();
    }
#undef WLOADR
#undef WSTORE
#undef ALOAD
#undef COMPUTE

    // ---------------- phase 2: bias + gate -> h (fp32, kept in acc1) ----------
    #pragma unroll
    for (int nt = 0; nt < 8; ++nt) {
        const int n = nt * 16 + l15;
        const float bb1 = bf1[n], bb2 = bf2[n];
        #pragma unroll
        for (int mt = 0; mt < 2; ++mt)
            #pragma unroll
            for (int rj = 0; rj < 4; ++rj) {
                float x1 = acc1[mt][nt][rj] + bb1;
                float x2 = acc2[mt][nt][rj] + bb2;
                float g  = sigm(x1 + x2);
                acc1[mt][nt][rj] = x2 + g * (x1 - x2);
            }
    }

    // v_n (session row 31: mt=1, kg=3, rj=3)
    if (kg == 3) {
        #pragma unroll
        for (int nt = 0; nt < 8; ++nt) vn[w][nt * 16 + l15] = acc1[1][nt][3];
    }
    asm volatile("s_waitcnt lgkmcnt(0)" ::: "memory");

    // ---------------- phase 3: w1v = W1 @ v_n + b1 (per session, wave-local) --
    {
        const int n0 = l, n1 = l + 64;
        const float* w1r0 = W1 + (size_t)n0 * 128;
        const float* w1r1 = W1 + (size_t)n1 * 128;
        float s0 = 0.f, s1 = 0.f;
        #pragma unroll
        for (int kk = 0; kk < 128; kk += 4) {
            f32x4 vv = *(const f32x4*)&vn[w][kk];
            f32x4 u0 = *(const f32x4*)(w1r0 + kk);
            f32x4 u1 = *(const f32x4*)(w1r1 + kk);
            #pragma unroll
            for (int j = 0; j < 4; ++j) { s0 += u0[j] * vv[j]; s1 += u1[j] * vv[j]; }
        }
        w1v[w][n0] = s0 + b1[n0];
        w1v[w][n1] = s1 + b1[n1];
    }
    asm volatile("s_waitcnt lgkmcnt(0)" ::: "memory");

    // ---------------- phases 4-7 per wave (hbuf round-split: 4 waves then 4) --
    auto tail = [&](int wj) {
        short (*hb)[HP] = u.hbuf[wj];
        #pragma unroll
        for (int nt = 0; nt < 8; ++nt)
            #pragma unroll
            for (int mt = 0; mt < 2; ++mt)
                #pragma unroll
                for (int rj = 0; rj < 4; ++rj)
                    hb[16 * mt + kg * 4 + rj][nt * 16 + l15] = f2b(acc1[mt][nt][rj]);
        asm volatile("s_waitcnt lgkmcnt(0)" ::: "memory");

        // phase 4: w2h = h @ W2^T (bf16 MFMA, K=128)
        f32x4 accw[2][8];
        #pragma unroll
        for (int mt = 0; mt < 2; ++mt)
            #pragma unroll
            for (int nt = 0; nt < 8; ++nt) accw[mt][nt] = f32x4{0.f,0.f,0.f,0.f};
        #pragma unroll
        for (int ks = 0; ks < 4; ++ks) {
            const int kl = ks * 32 + kg * 8;
            s16x8 ah0 = *(const s16x8*)&hb[l15][kl];
            s16x8 ah1 = *(const s16x8*)&hb[16 + l15][kl];
            #pragma unroll
            for (int nt = 0; nt < 8; ++nt) {
                s16x8 bw = *(const s16x8*)&w2b[(size_t)(nt * 16 + l15) * 128 + kl];
                accw[0][nt] = MFMA16(ah0, bw, accw[0][nt]);
                accw[1][nt] = MFMA16(ah1, bw, accw[1][nt]);
            }
        }

        // phase 5: alpha[row] = qb + sum_n q_n * sigm(w1v_n + w2h + b2_n)
        float part[2][4];
        #pragma unroll
        for (int mt = 0; mt < 2; ++mt)
            #pragma unroll
            for (int rj = 0; rj < 4; ++rj) part[mt][rj] = 0.f;
        #pragma unroll
        for (int nt = 0; nt < 8; ++nt) {
            const int n = nt * 16 + l15;
            const float qn = qw[n], wv_ = w1v[w][n], bb = b2[n];
            #pragma unroll
            for (int mt = 0; mt < 2; ++mt)
                #pragma unroll
                for (int rj = 0; rj < 4; ++rj)
                    part[mt][rj] += qn * sigm(wv_ + accw[mt][nt][rj] + bb);
        }
        const float qbias = qb[0];
        #pragma unroll
        for (int mt = 0; mt < 2; ++mt)
            #pragma unroll
            for (int rj = 0; rj < 4; ++rj) {
                float v = part[mt][rj];
                v += __shfl_xor(v, 1); v += __shfl_xor(v, 2);
                v += __shfl_xor(v, 4); v += __shfl_xor(v, 8);
                part[mt][rj] = v + qbias;      // alpha for row 16*mt + kg*4 + rj
            }

        // phase 6: s_g[n] = sum_t alpha_t * h[t][n]  (fp32, in-register + shfl)
        #pragma unroll
        for (int nt = 0; nt < 8; ++nt) {
            float s = 0.f;
            #pragma unroll
            for (int mt = 0; mt < 2; ++mt)
                #pragma unroll
                for (int rj = 0; rj < 4; ++rj)
                    s += part[mt][rj] * acc1[mt][nt][rj];
            s += __shfl_xor(s, 16);
            s += __shfl_xor(s, 32);
            if (l < 16) sgl[w][nt * 16 + l15] = s;
        }
        asm volatile("s_waitcnt lgkmcnt(0)" ::: "memory");

        // phase 7: out = W3 @ [v_n ; s_g] + b3  (fp32)
        const int n0 = l, n1 = l + 64;
        const float* w3r0 = W3 + (size_t)n0 * 256;
        const float* w3r1 = W3 + (size_t)n1 * 256;
        float h0 = b3[n0], h1 = b3[n1];
        #pragma unroll
        for (int kk = 0; kk < 128; kk += 4) {
            f32x4 vv = *(const f32x4*)&vn[w][kk];
            f32x4 ss = *(const f32x4*)&sgl[w][kk];
            f32x4 a0 = *(const f32x4*)(w3r0 + kk);
            f32x4 a1 = *(const f32x4*)(w3r1 + kk);
            f32x4 c0 = *(const f32x4*)(w3r0 + 128 + kk);
            f32x4 c1 = *(const f32x4*)(w3r1 + 128 + kk);
            #pragma unroll
            for (int j = 0; j < 4; ++j) {
                h0 += a0[j] * vv[j] + c0[j] * ss[j];
                h1 += a1[j] * vv[j] + c1[j] * ss[j];
            }
        }
        out[(size_t)sess * 128 + n0] = h0;
        out[(size_t)sess * 128 + n1] = h1;
    };

    if (w < 4) tail(w);
    __syncthreads();          // round A readers done before round B overwrites hbuf
    if (w >= 4) tail(w - 4);
}

// ---- naive fallback (only if ws too small; correctness insurance) ------------
__global__ __launch_bounds__(128) void itemfusing_naive(
    const float* __restrict__ inter, const float* __restrict__ intra,
    const float* __restrict__ Wf1, const float* __restrict__ bf1,
    const float* __restrict__ Wf2, const float* __restrict__ bf2,
    const float* __restrict__ W1,  const float* __restrict__ b1,
    const float* __restrict__ W2,  const float* __restrict__ b2,
    const float* __restrict__ qw,  const float* __restrict__ qb,
    const float* __restrict__ W3,  const float* __restrict__ b3,
    float* __restrict__ out)
{
    __shared__ float h[32][128];
    __shared__ float vn[128], w1v[128], al[32], sg[128], red[128];
    const int n = threadIdx.x; const int sess = blockIdx.x;
    for (int t0 = 0; t0 < 32; ++t0) {
        const float* e1 = inter + (size_t)(sess * 32 + t0) * 1024;
        const float* e2 = intra + (size_t)(sess * 32 + t0) * 1024;
        const float* r1 = Wf1 + (size_t)n * 1024;
        const float* r2 = Wf2 + (size_t)n * 1024;
        float s1 = bf1[n], s2 = bf2[n];
        for (int k = 0; k < 1024; ++k) { s1 += e1[k] * r1[k]; s2 += e2[k] * r2[k]; }
        float g = sigm(s1 + s2);
        h[t0][n] = s2 + g * (s1 - s2);
    }
    __syncthreads();
    vn[n] = h[31][n];
    __syncthreads();
    { float a = b1[n]; const float* w1r = W1 + (size_t)n * 128;
      for (int k = 0; k < 128; ++k) a += w1r[k] * vn[k];
      w1v[n] = a; }
    __syncthreads();
    for (int t0 = 0; t0 < 32; ++t0) {
        float x = b2[n]; const float* w2r = W2 + (size_t)n * 128;
        for (int k = 0; k < 128; ++k) x += w2r[k] * h[t0][k];
        red[n] = qw[n] * sigm(w1v[n] + x); __syncthreads();
        for (int s_ = 64; s_ > 0; s_ >>= 1) { if (n < s_) red[n] += red[n + s_]; __syncthreads(); }
        if (n == 0) al[t0] = red[0] + qb[0];
        __syncthreads();
    }
    { float s = 0.f; for (int t0 = 0; t0 < 32; ++t0) s += al[t0] * h[t0][n];
      sg[n] = s; }
    __syncthreads();
    { float o = b3[n]; const float* w3r = W3 + (size_t)n * 256;
      for (int k = 0; k < 128; ++k) o += w3r[k] * vn[k] + w3r[128 + k] * sg[k];
      out[(size_t)sess * 128 + n] = o; }
}

extern "C" void kernel_launch(void* const* d_in, const int* in_sizes, int n_in,
                              void* d_out, int out_size, void* d_ws, size_t ws_size,
                              hipStream_t stream) {
    (void)n_in; (void)out_size;
    const float* inter = (const float*)d_in[0];
    const float* intra = (const float*)d_in[1];
    const float* Wf1   = (const float*)d_in[3];
    const float* bf1   = (const float*)d_in[4];
    const float* Wf2   = (const float*)d_in[5];
    const float* bf2   = (const float*)d_in[6];
    const float* W1    = (const float*)d_in[7];
    const float* b1    = (const float*)d_in[8];
    const float* W2    = (const float*)d_in[9];
    const float* b2    = (const float*)d_in[10];
    const float* qw    = (const float*)d_in[11];
    const float* qb    = (const float*)d_in[12];
    const float* W3    = (const float*)d_in[13];
    const float* b3    = (const float*)d_in[14];
    float* out = (float*)d_out;

    const int nsess = in_sizes[2];               // 4096
    const size_t WS_NEED = (size_t)(524288 + 16384) * sizeof(short);

    if (d_ws != nullptr && ws_size >= WS_NEED) {
        short* wsp = (short*)d_ws;
        itemfusing_prep<<<264, 256, 0, stream>>>(Wf1, Wf2, W2, wsp);
        itemfusing_main<<<nsess / 8, THREADS, 0, stream>>>(
            inter, intra, bf1, bf2, W1, b1, b2, qw, qb, W3, b3,
            wsp, wsp + 524288, out);
    } else {
        itemfusing_naive<<<nsess, 128, 0, stream>>>(
            inter, intra, Wf1, bf1, Wf2, bf2, W1, b1, W2, b2, qw, qb, W3, b3, out);
    }
}

// Round 8
// 381.664 us; speedup vs baseline: 1.4593x; 1.0040x over previous
//
#include <hip/hip_runtime.h>
#include <hip/hip_bf16.h>

#define THREADS 512
#define HP 136     // padded LDS row stride (shorts) for h rows

typedef float f32x4 __attribute__((ext_vector_type(4)));
typedef short s16x8 __attribute__((ext_vector_type(8)));

static __device__ __forceinline__ short f2b(float x) {
    return __builtin_bit_cast(short, __float2bfloat16(x));
}
static __device__ __forceinline__ float b2f(short u) {
    unsigned int v = ((unsigned int)(unsigned short)u) << 16;
    return __builtin_bit_cast(float, v);
}
static __device__ __forceinline__ void split8(const f32x4 a, const f32x4 b, s16x8& hi, s16x8& lo) {
    #pragma unroll
    for (int j = 0; j < 4; ++j) {
        short h0 = f2b(a[j]); hi[j]   = h0; lo[j]   = f2b(a[j] - b2f(h0));
        short h1 = f2b(b[j]); hi[j+4] = h1; lo[j+4] = f2b(b[j] - b2f(h1));
    }
}
static __device__ __forceinline__ s16x8 cvt8(const f32x4 a, const f32x4 b) {
    s16x8 r;
    r[0]=f2b(a[0]); r[1]=f2b(a[1]); r[2]=f2b(a[2]); r[3]=f2b(a[3]);
    r[4]=f2b(b[0]); r[5]=f2b(b[1]); r[6]=f2b(b[2]); r[7]=f2b(b[3]);
    return r;
}
static __device__ __forceinline__ float sigm(float x) { return 1.0f / (1.0f + __expf(-x)); }

#define MFMA16(A,B,C) __builtin_amdgcn_mfma_f32_16x16x32_bf16((A),(B),(C),0,0,0)

// Raw barrier: retire this wave's LDS ops, do NOT drain vmcnt (prefetches
// stay in flight across the barrier — this is the whole point of this round).
#define RAWBAR() do {                                               \
    asm volatile("s_waitcnt lgkmcnt(0)" ::: "memory");              \
    __builtin_amdgcn_s_barrier();                                   \
    asm volatile("" ::: "memory"); } while (0)

// ---- pre-pass: build XOR-swizzled hi/lo weight image + W2 bf16 ---------------
// image (shorts): chunk cp (32 KB): [fz][plane][n][slot*8], slot = kg ^ ((n>>1)&3)
// 32 chunks * 16384 shorts = 524288 (1 MB); then W2 bf16 [128][128] = 16384.
__global__ __launch_bounds__(256) void itemfusing_prep(
    const float* __restrict__ Wf1, const float* __restrict__ Wf2,
    const float* __restrict__ W2, short* __restrict__ wsp)
{
    const int t = blockIdx.x * 256 + threadIdx.x;
    if (t < 65536) {
        const int kg = t & 3;
        const int n  = (t >> 2) & 127;
        const int pl = (t >> 9) & 1;
        const int cp = (t >> 10) & 31;
        const int fz = (t >> 15) & 1;
        const float* src = (fz ? Wf2 : Wf1) + (size_t)n * 1024 + cp * 32 + kg * 8;
        s16x8 hi, lo; split8(*(const f32x4*)src, *(const f32x4*)(src + 4), hi, lo);
        const int slot = kg ^ ((n >> 1) & 3);
        *(s16x8*)(wsp + (size_t)cp * 16384 + fz * 8192 + pl * 4096 + n * 32 + slot * 8)
            = pl ? lo : hi;
    } else if (t < 65536 + 2048) {
        const int i = (t - 65536) * 8;
        const float* src = W2 + i;
        *(s16x8*)(wsp + 524288 + i) = cvt8(*(const f32x4*)src, *(const f32x4*)(src + 4));
    }
}

// ---- main: R7 structure (512 thr, 8 waves = 8 sessions, M=32/wave) -----------
// Identical to round 7 except the 65 phase-1 barriers are raw (no vmcnt drain).
__global__ __launch_bounds__(THREADS, 2) void itemfusing_main(
    const float* __restrict__ inter, const float* __restrict__ intra,
    const float* __restrict__ bf1, const float* __restrict__ bf2,
    const float* __restrict__ W1,  const float* __restrict__ b1,
    const float* __restrict__ b2,
    const float* __restrict__ qw,  const float* __restrict__ qb,
    const float* __restrict__ W3,  const float* __restrict__ b3,
    const short* __restrict__ gimg, const short* __restrict__ w2b,
    float* __restrict__ out)
{
    __shared__ union {
        short wbuf[2][2][128][32];   // [weight-buf][plane][n][k-slot] : 32768 B
        short hbuf[4][32][HP];       // h rows for 4 waves            : 34816 B
    } u;
    __shared__ float vn [8][128];    // 4096 B
    __shared__ float w1v[8][128];    // 4096 B
    __shared__ float sgl[8][128];    // 4096 B   -> static total 47104 B

    const int tid = threadIdx.x;
    const int w   = tid >> 6;        // wave id == session slot (0..7)
    const int l   = tid & 63;
    const int l15 = l & 15;
    const int kg  = l >> 4;
    const int sess = blockIdx.x * 8 + w;
    const int row0 = sess * 32;
    const int slot8 = (kg ^ ((l15 >> 1) & 3)) * 8;

    const float* A1 = inter + (size_t)(row0 + l15) * 1024 + kg * 8;
    const float* A2 = intra + (size_t)(row0 + l15) * 1024 + kg * 8;
    short* wb = &u.wbuf[0][0][0][0];

    f32x4 acc1[2][8], acc2[2][8];
    #pragma unroll
    for (int mt = 0; mt < 2; ++mt)
        #pragma unroll
        for (int nt = 0; nt < 8; ++nt) {
            acc1[mt][nt] = f32x4{0.f,0.f,0.f,0.f};
            acc2[mt][nt] = f32x4{0.f,0.f,0.f,0.f};
        }

    // staging: thread copies 16 shorts of one weight chunk (8192 shorts / 512 thr)
    s16x8 wrA, wrB;
#define WLOADR(FZ, CP) do {                                                     \
    const short* p_ = gimg + (size_t)(CP) * 16384 + (FZ) * 8192 + tid * 16;     \
    wrA = *(const s16x8*)p_; wrB = *(const s16x8*)(p_ + 8); } while (0)
#define WSTORE(BUF) do {                                                        \
    short* d_ = wb + (BUF) * 8192 + tid * 16;                                   \
    *(s16x8*)d_ = wrA; *(s16x8*)(d_ + 8) = wrB; } while (0)
#define ALOAD(R0, R1, R2_, R3_, AP, CP) do {                                    \
    const float* p_ = (AP) + (CP) * 32;                                         \
    R0 = *(const f32x4*)p_;  R1 = *(const f32x4*)(p_ + 4);                      \
    const float* q_ = p_ + (size_t)16 * 1024;                                   \
    R2_ = *(const f32x4*)q_; R3_ = *(const f32x4*)(q_ + 4); } while (0)
#define COMPUTE(BUF, ACC, R0, R1, R2_, R3_) do {                                \
    s16x8 ah0, al0, ah1, al1;                                                   \
    split8(R0, R1, ah0, al0);                                                   \
    split8(R2_, R3_, ah1, al1);                                                 \
    const short* fb_ = wb + (BUF) * 8192 + l15 * 32 + slot8;                    \
    _Pragma("unroll")                                                           \
    for (int nt_ = 0; nt_ < 8; ++nt_) {                                         \
        s16x8 bh_ = *(const s16x8*)(fb_ + nt_ * 512);                           \
        s16x8 bl_ = *(const s16x8*)(fb_ + 4096 + nt_ * 512);                    \
        ACC[0][nt_] = MFMA16(ah0, bh_, ACC[0][nt_]);                            \
        ACC[1][nt_] = MFMA16(ah1, bh_, ACC[1][nt_]);                            \
        ACC[0][nt_] = MFMA16(al0, bh_, ACC[0][nt_]);                            \
        ACC[1][nt_] = MFMA16(al1, bh_, ACC[1][nt_]);                            \
        ACC[0][nt_] = MFMA16(ah0, bl_, ACC[0][nt_]);                            \
        ACC[1][nt_] = MFMA16(ah1, bl_, ACC[1][nt_]);                            \
    } } while (0)

    f32x4 r10, r11, r12, r13;   // A(inter) regs
    f32x4 r20, r21, r22, r23;   // A(intra) regs

    // prologue: buf0 <- Wf1 c0; regs <- Wf2 c0; A regs <- c0
    WLOADR(0, 0); WSTORE(0);
    WLOADR(1, 0);
    ALOAD(r10, r11, r12, r13, A1, 0);
    ALOAD(r20, r21, r22, r23, A2, 0);
    RAWBAR();

    #pragma unroll 1
    for (int cp = 0; cp < 32; ++cp) {
        const bool more = (cp < 31);
        {   // EVEN: stage Wf2 cp -> buf1; prefetch Wf1 cp+1; compute acc1 from buf0
            WSTORE(1);
            if (more) WLOADR(0, cp + 1);
            COMPUTE(0, acc1, r10, r11, r12, r13);
            if (more) ALOAD(r10, r11, r12, r13, A1, cp + 1);
        }
        RAWBAR();
        {   // ODD: stage Wf1 cp+1 -> buf0; prefetch Wf2 cp+1; compute acc2 from buf1
            if (more) { WSTORE(0); WLOADR(1, cp + 1); }
            COMPUTE(1, acc2, r20, r21, r22, r23);
            if (more) ALOAD(r20, r21, r22, r23, A2, cp + 1);
        }
        RAWBAR();
    }
#undef WLOADR
#undef WSTORE
#undef ALOAD
#undef COMPUTE

    // ---------------- phase 2: bias + gate -> h (fp32, kept in acc1) ----------
    #pragma unroll
    for (int nt = 0; nt < 8; ++nt) {
        const int n = nt * 16 + l15;
        const float bb1 = bf1[n], bb2 = bf2[n];
        #pragma unroll
        for (int mt = 0; mt < 2; ++mt)
            #pragma unroll
            for (int rj = 0; rj < 4; ++rj) {
                float x1 = acc1[mt][nt][rj] + bb1;
                float x2 = acc2[mt][nt][rj] + bb2;
                float g  = sigm(x1 + x2);
                acc1[mt][nt][rj] = x2 + g * (x1 - x2);
            }
    }

    // v_n (session row 31: mt=1, kg=3, rj=3)
    if (kg == 3) {
        #pragma unroll
        for (int nt = 0; nt < 8; ++nt) vn[w][nt * 16 + l15] = acc1[1][nt][3];
    }
    asm volatile("s_waitcnt lgkmcnt(0)" ::: "memory");

    // ---------------- phase 3: w1v = W1 @ v_n + b1 (per session, wave-local) --
    {
        const int n0 = l, n1 = l + 64;
        const float* w1r0 = W1 + (size_t)n0 * 128;
        const float* w1r1 = W1 + (size_t)n1 * 128;
        float s0 = 0.f, s1 = 0.f;
        #pragma unroll
        for (int kk = 0; kk < 128; kk += 4) {
            f32x4 vv = *(const f32x4*)&vn[w][kk];
            f32x4 u0 = *(const f32x4*)(w1r0 + kk);
            f32x4 u1 = *(const f32x4*)(w1r1 + kk);
            #pragma unroll
            for (int j = 0; j < 4; ++j) { s0 += u0[j] * vv[j]; s1 += u1[j] * vv[j]; }
        }
        w1v[w][n0] = s0 + b1[n0];
        w1v[w][n1] = s1 + b1[n1];
    }
    asm volatile("s_waitcnt lgkmcnt(0)" ::: "memory");

    // ---------------- phases 4-7 per wave (hbuf round-split: 4 waves then 4) --
    auto tail = [&](int wj) {
        short (*hb)[HP] = u.hbuf[wj];
        #pragma unroll
        for (int nt = 0; nt < 8; ++nt)
            #pragma unroll
            for (int mt = 0; mt < 2; ++mt)
                #pragma unroll
                for (int rj = 0; rj < 4; ++rj)
                    hb[16 * mt + kg * 4 + rj][nt * 16 + l15] = f2b(acc1[mt][nt][rj]);
        asm volatile("s_waitcnt lgkmcnt(0)" ::: "memory");

        // phase 4: w2h = h @ W2^T (bf16 MFMA, K=128)
        f32x4 accw[2][8];
        #pragma unroll
        for (int mt = 0; mt < 2; ++mt)
            #pragma unroll
            for (int nt = 0; nt < 8; ++nt) accw[mt][nt] = f32x4{0.f,0.f,0.f,0.f};
        #pragma unroll
        for (int ks = 0; ks < 4; ++ks) {
            const int kl = ks * 32 + kg * 8;
            s16x8 ah0 = *(const s16x8*)&hb[l15][kl];
            s16x8 ah1 = *(const s16x8*)&hb[16 + l15][kl];
            #pragma unroll
            for (int nt = 0; nt < 8; ++nt) {
                s16x8 bw = *(const s16x8*)&w2b[(size_t)(nt * 16 + l15) * 128 + kl];
                accw[0][nt] = MFMA16(ah0, bw, accw[0][nt]);
                accw[1][nt] = MFMA16(ah1, bw, accw[1][nt]);
            }
        }

        // phase 5: alpha[row] = qb + sum_n q_n * sigm(w1v_n + w2h + b2_n)
        float part[2][4];
        #pragma unroll
        for (int mt = 0; mt < 2; ++mt)
            #pragma unroll
            for (int rj = 0; rj < 4; ++rj) part[mt][rj] = 0.f;
        #pragma unroll
        for (int nt = 0; nt < 8; ++nt) {
            const int n = nt * 16 + l15;
            const float qn = qw[n], wv_ = w1v[w][n], bb = b2[n];
            #pragma unroll
            for (int mt = 0; mt < 2; ++mt)
                #pragma unroll
                for (int rj = 0; rj < 4; ++rj)
                    part[mt][rj] += qn * sigm(wv_ + accw[mt][nt][rj] + bb);
        }
        const float qbias = qb[0];
        #pragma unroll
        for (int mt = 0; mt < 2; ++mt)
            #pragma unroll
            for (int rj = 0; rj < 4; ++rj) {
                float v = part[mt][rj];
                v += __shfl_xor(v, 1); v += __shfl_xor(v, 2);
                v += __shfl_xor(v, 4); v += __shfl_xor(v, 8);
                part[mt][rj] = v + qbias;      // alpha for row 16*mt + kg*4 + rj
            }

        // phase 6: s_g[n] = sum_t alpha_t * h[t][n]  (fp32, in-register + shfl)
        #pragma unroll
        for (int nt = 0; nt < 8; ++nt) {
            float s = 0.f;
            #pragma unroll
            for (int mt = 0; mt < 2; ++mt)
                #pragma unroll
                for (int rj = 0; rj < 4; ++rj)
                    s += part[mt][rj] * acc1[mt][nt][rj];
            s += __shfl_xor(s, 16);
            s += __shfl_xor(s, 32);
            if (l < 16) sgl[w][nt * 16 + l15] = s;
        }
        asm volatile("s_waitcnt lgkmcnt(0)" ::: "memory");

        // phase 7: out = W3 @ [v_n ; s_g] + b3  (fp32)
        const int n0 = l, n1 = l + 64;
        const float* w3r0 = W3 + (size_t)n0 * 256;
        const float* w3r1 = W3 + (size_t)n1 * 256;
        float h0 = b3[n0], h1 = b3[n1];
        #pragma unroll
        for (int kk = 0; kk < 128; kk += 4) {
            f32x4 vv = *(const f32x4*)&vn[w][kk];
            f32x4 ss = *(const f32x4*)&sgl[w][kk];
            f32x4 a0 = *(const f32x4*)(w3r0 + kk);
            f32x4 a1 = *(const f32x4*)(w3r1 + kk);
            f32x4 c0 = *(const f32x4*)(w3r0 + 128 + kk);
            f32x4 c1 = *(const f32x4*)(w3r1 + 128 + kk);
            #pragma unroll
            for (int j = 0; j < 4; ++j) {
                h0 += a0[j] * vv[j] + c0[j] * ss[j];
                h1 += a1[j] * vv[j] + c1[j] * ss[j];
            }
        }
        out[(size_t)sess * 128 + n0] = h0;
        out[(size_t)sess * 128 + n1] = h1;
    };

    if (w < 4) tail(w);
    __syncthreads();          // round A readers done before round B overwrites hbuf
    if (w >= 4) tail(w - 4);
}

// ---- naive fallback (only if ws too small; correctness insurance) ------------
__global__ __launch_bounds__(128) void itemfusing_naive(
    const float* __restrict__ inter, const float* __restrict__ intra,
    const float* __restrict__ Wf1, const float* __restrict__ bf1,
    const float* __restrict__ Wf2, const float* __restrict__ bf2,
    const float* __restrict__ W1,  const float* __restrict__ b1,
    const float* __restrict__ W2,  const float* __restrict__ b2,
    const float* __restrict__ qw,  const float* __restrict__ qb,
    const float* __restrict__ W3,  const float* __restrict__ b3,
    float* __restrict__ out)
{
    __shared__ float h[32][128];
    __shared__ float vn[128], w1v[128], al[32], sg[128], red[128];
    const int n = threadIdx.x; const int sess = blockIdx.x;
    for (int t0 = 0; t0 < 32; ++t0) {
        const float* e1 = inter + (size_t)(sess * 32 + t0) * 1024;
        const float* e2 = intra + (size_t)(sess * 32 + t0) * 1024;
        const float* r1 = Wf1 + (size_t)n * 1024;
        const float* r2 = Wf2 + (size_t)n * 1024;
        float s1 = bf1[n], s2 = bf2[n];
        for (int k = 0; k < 1024; ++k) { s1 += e1[k] * r1[k]; s2 += e2[k] * r2[k]; }
        float g = sigm(s1 + s2);
        h[t0][n] = s2 + g * (s1 - s2);
    }
    __syncthreads();
    vn[n] = h[31][n];
    __syncthreads();
    { float a = b1[n]; const float* w1r = W1 + (size_t)n * 128;
      for (int k = 0; k < 128; ++k) a += w1r[k] * vn[k];
      w1v[n] = a; }
    __syncthreads();
    for (int t0 = 0; t0 < 32; ++t0) {
        float x = b2[n]; const float* w2r = W2 + (size_t)n * 128;
        for (int k = 0; k < 128; ++k) x += w2r[k] * h[t0][k];
        red[n] = qw[n] * sigm(w1v[n] + x); __syncthreads();
        for (int s_ = 64; s_ > 0; s_ >>= 1) { if (n < s_) red[n] += red[n + s_]; __syncthreads(); }
        if (n == 0) al[t0] = red[0] + qb[0];
        __syncthreads();
    }
    { float s = 0.f; for (int t0 = 0; t0 < 32; ++t0) s += al[t0] * h[t0][n];
      sg[n] = s; }
    __syncthreads();
    { float o = b3[n]; const float* w3r = W3 + (size_t)n * 256;
      for (int k = 0; k < 128; ++k) o += w3r[k] * vn[k] + w3r[128 + k] * sg[k];
      out[(size_t)sess * 128 + n] = o; }
}

extern "C" void kernel_launch(void* const* d_in, const int* in_sizes, int n_in,
                              void* d_out, int out_size, void* d_ws, size_t ws_size,
                              hipStream_t stream) {
    (void)n_in; (void)out_size;
    const float* inter = (const float*)d_in[0];
    const float* intra = (const float*)d_in[1];
    const float* Wf1   = (const float*)d_in[3];
    const float* bf1   = (const float*)d_in[4];
    const float* Wf2   = (const float*)d_in[5];
    const float* bf2   = (const float*)d_in[6];
    const float* W1    = (const float*)d_in[7];
    const float* b1    = (const float*)d_in[8];
    const float* W2    = (const float*)d_in[9];
    const float* b2    = (const float*)d_in[10];
    const float* qw    = (const float*)d_in[11];
    const float* qb    = (const float*)d_in[12];
    const float* W3    = (const float*)d_in[13];
    const float* b3    = (const float*)d_in[14];
    float* out = (float*)d_out;

    const int nsess = in_sizes[2];               // 4096
    const size_t WS_NEED = (size_t)(524288 + 16384) * sizeof(short);

    if (d_ws != nullptr && ws_size >= WS_NEED) {
        short* wsp = (short*)d_ws;
        itemfusing_prep<<<264, 256, 0, stream>>>(Wf1, Wf2, W2, wsp);
        itemfusing_main<<<nsess / 8, THREADS, 0, stream>>>(
            inter, intra, bf1, bf2, W1, b1, b2, qw, qb, W3, b3,
            wsp, wsp + 524288, out);
    } else {
        itemfusing_naive<<<nsess, 128, 0, stream>>>(
            inter, intra, Wf1, bf1, Wf2, bf2, W1, b1, W2, b2, qw, qb, W3, b3, out);
    }
}